// Round 2
// baseline (34095.325 us; speedup 1.0000x reference)
//
#include <hip/hip_runtime.h>

#define Ssz 512
#define Hsz 512
#define G3  1536
#define BT  32
#define NW  16
#define WGS 1024

typedef __attribute__((ext_vector_type(8))) short short8;
typedef __attribute__((ext_vector_type(4))) float f32x4;

__device__ __forceinline__ unsigned short f2bf(float f) {
  unsigned int u = __builtin_bit_cast(unsigned int, f);
  u += 0x7fffu + ((u >> 16) & 1u);   // RNE (finite inputs)
  return (unsigned short)(u >> 16);
}

__device__ __forceinline__ float sigm(float x) {
  x = fminf(fmaxf(x, -30.f), 30.f);
  return 1.f / (1.f + __expf(-x));
}
__device__ __forceinline__ float tanh_f(float x) {
  x = fminf(fmaxf(x, -15.f), 15.f);
  float e = __expf(2.f * x);
  return (e - 1.f) / (e + 1.f);
}

// Pack W_hh [1536,512] f32 -> fragment-ordered bf16.
// byte offset (((w*6+q)*16+kk)*64+l)*16 ; q = gate*2+th
// holds W_hh[gate*512 + w*32 + th*16 + (l&15)][kk*32 + (l>>4)*8 + e]
__global__ void pack_whh_k(const float* __restrict__ Wp, unsigned short* __restrict__ dst) {
  int T = blockIdx.x * 256 + threadIdx.x;      // 98304 threads
  int l  = T & 63;
  int r1 = T >> 6;
  int kk = r1 & 15;
  int r2 = r1 >> 4;
  int q  = r2 % 6;
  int w  = r2 / 6;
  int g = q >> 1, th = q & 1;
  int j  = g * 512 + w * 32 + th * 16 + (l & 15);
  int kb = kk * 32 + (l >> 4) * 8;
  const float* src = Wp + j * 512 + kb;
  short8 o;
#pragma unroll
  for (int e = 0; e < 8; ++e) o[e] = (short)f2bf(src[e]);
  *reinterpret_cast<short8*>(dst + (size_t)T * 8) = o;
}

// Pack W1 [256,512] f32 -> fragment-ordered bf16.
// byte offset ((w*16+kk)*64+l)*16 holds W1[w*16+(l&15)][kk*32+(l>>4)*8+e]
__global__ void pack_w1_k(const float* __restrict__ W1, unsigned short* __restrict__ dst) {
  int T = blockIdx.x * 256 + threadIdx.x;      // 16384 threads
  int l  = T & 63;
  int r1 = T >> 6;
  int kk = r1 & 15;
  int w  = r1 >> 4;
  int j  = w * 16 + (l & 15);
  int kb = kk * 32 + (l >> 4) * 8;
  const float* src = W1 + j * 512 + kb;
  short8 o;
#pragma unroll
  for (int e = 0; e < 8; ++e) o[e] = (short)f2bf(src[e]);
  *reinterpret_cast<short8*>(dst + (size_t)T * 8) = o;
}

// 32 WGs, one per 32-row batch tile; 16 waves; wave w owns h-cols
// [w*32, w*32+32) (3 gates x 2 col-tiles) + MLP cols [w*16, w*16+16).
// Each B-fragment feeds 2 row-tiles (rt=0,1). h fp32 master lives in VGPRs.
__global__ __launch_bounds__(1024) void gru_main(
    const float* __restrict__ X0, const float* __restrict__ V,
    const float* __restrict__ Wih, const float* __restrict__ bih_g,
    const float* __restrict__ bhh_g, const float* __restrict__ b1_g,
    const float* __restrict__ W2_g, const float* __restrict__ b2_g,
    const unsigned short* __restrict__ PW, const unsigned short* __restrict__ PW1,
    float* __restrict__ out)
{
  __shared__ alignas(16) unsigned short hb[BT * Hsz];   // 32 KB bf16 mirror (swizzled 16B slots)
  __shared__ float bihs[G3];
  __shared__ float bhhs[G3];
  __shared__ alignas(16) float gin[BT][4];              // [v0,v1,x0,x1] per row
  __shared__ float xprev[BT][2];
  __shared__ float part[NW][BT][2];

  const int tid = threadIdx.x;
  const int l   = tid & 63;
  const int w   = tid >> 6;
  const int lm  = l & 15;
  const int ld  = l >> 4;
  const int row0 = blockIdx.x * BT;

  for (int i = tid; i < G3; i += WGS) { bihs[i] = bih_g[i]; bhhs[i] = bhh_g[i]; }
  for (int i = tid; i < BT * Hsz; i += WGS) hb[i] = 0;
  if (tid < BT * 2) {
    int m = tid >> 1, c = tid & 1;
    float x0 = X0[(row0 + m) * 2 + c];
    xprev[m][c]   = x0;
    gin[m][2 + c] = x0;
    gin[m][c]     = V[(size_t)(row0 + m) * (Ssz * 2) + c];   // v_0
  }
  __syncthreads();

  const char* hbB  = reinterpret_cast<const char*>(hb);
  char*       hbW  = reinterpret_cast<char*>(hb);
  const char* pwB  = reinterpret_cast<const char*>(PW)  + (size_t)w * (6 * 16 * 1024);
  const char* pw1B = reinterpret_cast<const char*>(PW1) + (size_t)w * (16 * 1024);
  const int ab0  = lm * 1024 + ld * 16;          // A-frag rowtile 0: row lm
  const int ab1  = (16 + lm) * 1024 + ld * 16;   // A-frag rowtile 1: row 16+lm
  const int aswz = (lm & 7) << 4;
  const int jh0  = w * 32;
  const f32x4* Wih4 = reinterpret_cast<const f32x4*>(Wih);

  float hp[2][2][4];                              // fp32 h master: [rt][th][r]
#pragma unroll
  for (int rt = 0; rt < 2; ++rt)
#pragma unroll
    for (int th = 0; th < 2; ++th)
#pragma unroll
      for (int r = 0; r < 4; ++r) hp[rt][th][r] = 0.f;

  for (int t = 0; t < Ssz; ++t) {
    // ======== gates: two sweeps (th=0, th=1), each 3 col-tiles x 2 row-tiles ====
#pragma unroll
    for (int th = 0; th < 2; ++th) {
      f32x4 acc[2][3];
#pragma unroll
      for (int rt = 0; rt < 2; ++rt)
#pragma unroll
        for (int g = 0; g < 3; ++g) acc[rt][g] = (f32x4){0.f, 0.f, 0.f, 0.f};

      const char* pq0 = pwB + (0 * 2 + th) * 16384 + l * 16;
      const char* pq1 = pwB + (1 * 2 + th) * 16384 + l * 16;
      const char* pq2 = pwB + (2 * 2 + th) * 16384 + l * 16;
      short8 bA0 = *reinterpret_cast<const short8*>(pq0);
      short8 bA1 = *reinterpret_cast<const short8*>(pq1);
      short8 bA2 = *reinterpret_cast<const short8*>(pq2);
#pragma unroll
      for (int kk = 0; kk < 16; kk += 2) {
        const int o1 = (kk + 1) * 1024;
        short8 bB0 = *reinterpret_cast<const short8*>(pq0 + o1);
        short8 bB1 = *reinterpret_cast<const short8*>(pq1 + o1);
        short8 bB2 = *reinterpret_cast<const short8*>(pq2 + o1);
        short8 a0 = *reinterpret_cast<const short8*>(hbB + ((ab0 + kk * 64) ^ aswz));
        short8 a1 = *reinterpret_cast<const short8*>(hbB + ((ab1 + kk * 64) ^ aswz));
        acc[0][0] = __builtin_amdgcn_mfma_f32_16x16x32_bf16(a0, bA0, acc[0][0], 0, 0, 0);
        acc[1][0] = __builtin_amdgcn_mfma_f32_16x16x32_bf16(a1, bA0, acc[1][0], 0, 0, 0);
        acc[0][1] = __builtin_amdgcn_mfma_f32_16x16x32_bf16(a0, bA1, acc[0][1], 0, 0, 0);
        acc[1][1] = __builtin_amdgcn_mfma_f32_16x16x32_bf16(a1, bA1, acc[1][1], 0, 0, 0);
        acc[0][2] = __builtin_amdgcn_mfma_f32_16x16x32_bf16(a0, bA2, acc[0][2], 0, 0, 0);
        acc[1][2] = __builtin_amdgcn_mfma_f32_16x16x32_bf16(a1, bA2, acc[1][2], 0, 0, 0);
        if (kk + 2 < 16) {
          const int o2 = (kk + 2) * 1024;
          bA0 = *reinterpret_cast<const short8*>(pq0 + o2);
          bA1 = *reinterpret_cast<const short8*>(pq1 + o2);
          bA2 = *reinterpret_cast<const short8*>(pq2 + o2);
        }
        a0 = *reinterpret_cast<const short8*>(hbB + ((ab0 + (kk + 1) * 64) ^ aswz));
        a1 = *reinterpret_cast<const short8*>(hbB + ((ab1 + (kk + 1) * 64) ^ aswz));
        acc[0][0] = __builtin_amdgcn_mfma_f32_16x16x32_bf16(a0, bB0, acc[0][0], 0, 0, 0);
        acc[1][0] = __builtin_amdgcn_mfma_f32_16x16x32_bf16(a1, bB0, acc[1][0], 0, 0, 0);
        acc[0][1] = __builtin_amdgcn_mfma_f32_16x16x32_bf16(a0, bB1, acc[0][1], 0, 0, 0);
        acc[1][1] = __builtin_amdgcn_mfma_f32_16x16x32_bf16(a1, bB1, acc[1][1], 0, 0, 0);
        acc[0][2] = __builtin_amdgcn_mfma_f32_16x16x32_bf16(a0, bB2, acc[0][2], 0, 0, 0);
        acc[1][2] = __builtin_amdgcn_mfma_f32_16x16x32_bf16(a1, bB2, acc[1][2], 0, 0, 0);
      }

      if (th == 0) __syncthreads();   // B1: finisher(t-1) done -> gin/xprev valid

      // ---- gate math for this th (updates hp in registers; hb write deferred) ----
      {
        const int jh = jh0 + th * 16 + lm;
        const f32x4 wr = Wih4[jh];
        const f32x4 wz = Wih4[512 + jh];
        const f32x4 wn = Wih4[1024 + jh];
        const float bir = bihs[jh],        bhr = bhhs[jh];
        const float biz = bihs[512 + jh],  bhz = bhhs[512 + jh];
        const float bin = bihs[1024 + jh], bhn = bhhs[1024 + jh];
#pragma unroll
        for (int rt = 0; rt < 2; ++rt) {
#pragma unroll
          for (int r = 0; r < 4; ++r) {
            const int m = rt * 16 + ld * 4 + r;
            const f32x4 g4 = *reinterpret_cast<const f32x4*>(&gin[m][0]);
            float gr = wr[0]*g4[0] + wr[1]*g4[1] + wr[2]*g4[2] + wr[3]*g4[3] + bir
                     + acc[rt][0][r] + bhr;
            float gz = wz[0]*g4[0] + wz[1]*g4[1] + wz[2]*g4[2] + wz[3]*g4[3] + biz
                     + acc[rt][1][r] + bhz;
            float hn = acc[rt][2][r] + bhn;
            float gn = wn[0]*g4[0] + wn[1]*g4[1] + wn[2]*g4[2] + wn[3]*g4[3] + bin;
            float rr = sigm(gr);
            float zz = sigm(gz);
            float nn = tanh_f(gn + rr * hn);
            hp[rt][th][r] = (1.f - zz) * nn + zz * hp[rt][th][r];
          }
        }
      }
    }
    __syncthreads();   // B2: all waves done reading h_{t-1} mirror

    // ---- publish h_t bf16 mirror ----
#pragma unroll
    for (int rt = 0; rt < 2; ++rt)
#pragma unroll
      for (int th = 0; th < 2; ++th)
#pragma unroll
        for (int r = 0; r < 4; ++r) {
          const int m  = rt * 16 + ld * 4 + r;
          const int jh = jh0 + th * 16 + lm;
          *reinterpret_cast<unsigned short*>(hbW + ((m * 1024 + jh * 2) ^ ((m & 7) << 4)))
              = f2bf(hp[rt][th][r]);
        }
    __syncthreads();   // B3: h_t mirror ready

    // ---- residual MLP: m = relu(h_t @ W1^T + b1); res = m @ W2^T ----
    f32x4 am0 = (f32x4){0.f, 0.f, 0.f, 0.f};
    f32x4 am1 = (f32x4){0.f, 0.f, 0.f, 0.f};
    {
      const char* pm = pw1B + l * 16;
      short8 mb = *reinterpret_cast<const short8*>(pm);
#pragma unroll
      for (int kk = 0; kk < 16; ++kk) {
        const int kn = (kk + 1 < 16) ? (kk + 1) : 15;
        short8 mbn = *reinterpret_cast<const short8*>(pm + kn * 1024);
        short8 a0 = *reinterpret_cast<const short8*>(hbB + ((ab0 + kk * 64) ^ aswz));
        short8 a1 = *reinterpret_cast<const short8*>(hbB + ((ab1 + kk * 64) ^ aswz));
        am0 = __builtin_amdgcn_mfma_f32_16x16x32_bf16(a0, mb, am0, 0, 0, 0);
        am1 = __builtin_amdgcn_mfma_f32_16x16x32_bf16(a1, mb, am1, 0, 0, 0);
        mb = mbn;
      }
    }
    {
      const int ic = w * 16 + lm;
      const float b1v = b1_g[ic];
      const float w2a = W2_g[ic];          // W2[0][ic]
      const float w2b = W2_g[256 + ic];    // W2[1][ic]
      float pa[2][4], pb[2][4];
#pragma unroll
      for (int r = 0; r < 4; ++r) {
        float mv0 = fmaxf(am0[r] + b1v, 0.f);
        float mv1 = fmaxf(am1[r] + b1v, 0.f);
        pa[0][r] = mv0 * w2a;  pb[0][r] = mv0 * w2b;
        pa[1][r] = mv1 * w2a;  pb[1][r] = mv1 * w2b;
      }
#pragma unroll
      for (int off = 1; off < 16; off <<= 1) {
#pragma unroll
        for (int rt = 0; rt < 2; ++rt)
#pragma unroll
          for (int r = 0; r < 4; ++r) {
            pa[rt][r] += __shfl_xor(pa[rt][r], off);
            pb[rt][r] += __shfl_xor(pb[rt][r], off);
          }
      }
      if (lm == 0) {
#pragma unroll
        for (int rt = 0; rt < 2; ++rt)
#pragma unroll
          for (int r = 0; r < 4; ++r) {
            part[w][rt * 16 + ld * 4 + r][0] = pa[rt][r];
            part[w][rt * 16 + ld * 4 + r][1] = pb[rt][r];
          }
      }
    }
    __syncthreads();   // B4: partials ready; MLP hb reads done

    // ---- finisher: x_t = x_{t-1} + v_t + res; stage next step's inputs ----
    if (tid < BT * 2) {
      int m = tid >> 1, c = tid & 1;
      float s = b2_g[c];
#pragma unroll
      for (int ww = 0; ww < NW; ++ww) s += part[ww][m][c];
      float vt = gin[m][c];
      float xt = xprev[m][c] + vt + s;
      out[(size_t)(row0 + m) * (Ssz * 2) + t * 2 + c] = xt;
      xprev[m][c]   = xt;
      gin[m][2 + c] = xt;
      gin[m][c] = (t + 1 < Ssz) ? V[(size_t)(row0 + m) * (Ssz * 2) + (t + 1) * 2 + c] : 0.f;
    }
    // next gin/xprev readers are behind B1 of step t+1
  }
}

extern "C" void kernel_launch(void* const* d_in, const int* in_sizes, int n_in,
                              void* d_out, int out_size, void* d_ws, size_t ws_size,
                              hipStream_t stream) {
  const float* X0  = (const float*)d_in[0];
  const float* V   = (const float*)d_in[1];
  const float* Wih = (const float*)d_in[2];
  const float* Whh = (const float*)d_in[3];
  const float* bih = (const float*)d_in[4];
  const float* bhh = (const float*)d_in[5];
  const float* W1  = (const float*)d_in[6];
  const float* b1  = (const float*)d_in[7];
  const float* W2  = (const float*)d_in[8];
  const float* b2  = (const float*)d_in[9];
  float* out = (float*)d_out;

  // workspace: packed bf16 weights (1.5 MB + 0.25 MB)
  unsigned short* PW  = (unsigned short*)d_ws;
  unsigned short* PW1 = PW + (size_t)G3 * Hsz;

  pack_whh_k<<<384, 256, 0, stream>>>(Whh, PW);
  pack_w1_k<<<64, 256, 0, stream>>>(W1, PW1);
  gru_main<<<32, 1024, 0, stream>>>(X0, V, Wih, bih, bhh, b1, W2, b2, PW, PW1, out);
}

// Round 4
// 26102.496 us; speedup vs baseline: 1.3062x; 1.3062x over previous
//
#include <hip/hip_runtime.h>

#define Ssz 512
#define Hsz 512
#define BT  64     // rows per rowtile
#define NSL 16     // column slices
#define SLC 32     // h-cols per slice

typedef __attribute__((ext_vector_type(8))) short short8;
typedef __attribute__((ext_vector_type(4))) float f32x4;
typedef __attribute__((ext_vector_type(2))) float f32x2;

// ---- ws layout (bytes) ----
#define WS_PW   0u            // 1.5 MB packed gate weights
#define WS_PW1  1572864u      // 256 KB packed W1
#define WS_HB   1835008u      // 2 MB Hbuf[2][1024][512] bf16
#define WS_PX   3932160u      // 512 KB px[16][16][64][2] f32
#define WS_BAR  4456448u      // 4 KB barriers (16 x 64 uints)

__device__ __forceinline__ unsigned short f2bf(float f) {
  unsigned int u = __builtin_bit_cast(unsigned int, f);
  u += 0x7fffu + ((u >> 16) & 1u);   // RNE (finite inputs)
  return (unsigned short)(u >> 16);
}
__device__ __forceinline__ float sigm(float x) {
  x = fminf(fmaxf(x, -30.f), 30.f);
  return 1.f / (1.f + __expf(-x));
}
__device__ __forceinline__ float tanh_f(float x) {
  x = fminf(fmaxf(x, -15.f), 15.f);
  float e = __expf(2.f * x);
  return (e - 1.f) / (e + 1.f);
}

// Pack W_hh [1536,512] f32 -> fragment-ordered bf16.
// byte offset (((sl*6+q)*16+kk)*64+l)*16 ; q = gate*2+ch
// holds W_hh[gate*512 + sl*32 + ch*16 + (l&15)][kk*32 + (l>>4)*8 + e]
// Block 0 additionally zeroes ALL 1024 barrier words (every launch, so timed
// replays after the one-time 0xAA ws-poison stay deterministic).
__global__ void pack_whh_k(const float* __restrict__ Wp, unsigned short* __restrict__ dst,
                           unsigned* __restrict__ barz) {
  if (blockIdx.x == 0) {
    for (int i = threadIdx.x; i < 1024; i += 256) barz[i] = 0u;
  }
  int T = blockIdx.x * 256 + threadIdx.x;      // 98304 threads
  int l  = T & 63;
  int r1 = T >> 6;
  int kk = r1 & 15;
  int r2 = r1 >> 4;
  int q  = r2 % 6;
  int sl = r2 / 6;
  int g = q >> 1, ch = q & 1;
  int j  = g * 512 + sl * 32 + ch * 16 + (l & 15);
  int kb = kk * 32 + (l >> 4) * 8;
  const float* src = Wp + j * 512 + kb;
  short8 o;
#pragma unroll
  for (int e = 0; e < 8; ++e) o[e] = (short)f2bf(src[e]);
  *reinterpret_cast<short8*>(dst + (size_t)T * 8) = o;
}

// Pack W1 [256,512] f32 -> fragment-ordered bf16.
// byte offset ((sl*16+kk)*64+l)*16 holds W1[sl*16+(l&15)][kk*32+(l>>4)*8+e]
__global__ void pack_w1_k(const float* __restrict__ W1, unsigned short* __restrict__ dst) {
  int T = blockIdx.x * 256 + threadIdx.x;      // 16384 threads
  int l  = T & 63;
  int r1 = T >> 6;
  int kk = r1 & 15;
  int sl = r1 >> 4;
  int j  = sl * 16 + (l & 15);
  int kb = kk * 32 + (l >> 4) * 8;
  const float* src = W1 + j * 512 + kb;
  short8 o;
#pragma unroll
  for (int e = 0; e < 8; ++e) o[e] = (short)f2bf(src[e]);
  *reinterpret_cast<short8*>(dst + (size_t)T * 8) = o;
}

// 16-WG sense-reversing barrier (one per rowtile). Thread 0 pattern:
// syncthreads -> fence -> atomic arrive -> spin on gen -> fence -> syncthreads.
__device__ __forceinline__ void rtbar(unsigned* cnt, unsigned* gen) {
  __syncthreads();
  if (threadIdx.x == 0) {
    unsigned g0 = __hip_atomic_load(gen, __ATOMIC_RELAXED, __HIP_MEMORY_SCOPE_AGENT);
    __threadfence();
    unsigned old = __hip_atomic_fetch_add(cnt, 1u, __ATOMIC_ACQ_REL, __HIP_MEMORY_SCOPE_AGENT);
    if (old == 15u) {
      __hip_atomic_store(cnt, 0u, __ATOMIC_RELAXED, __HIP_MEMORY_SCOPE_AGENT);
      __hip_atomic_fetch_add(gen, 1u, __ATOMIC_RELEASE, __HIP_MEMORY_SCOPE_AGENT);
    } else {
      while (__hip_atomic_load(gen, __ATOMIC_ACQUIRE, __HIP_MEMORY_SCOPE_AGENT) == g0)
        __builtin_amdgcn_s_sleep(2);
    }
    __threadfence();
  }
  __syncthreads();
}

// 256 WGs x 256 threads, PLAIN launch (grid == CU count; ~330+ VGPR/wave with
// __launch_bounds__(256,1) forces 1 WG/CU, so all 256 WGs dispatch onto 256
// idle CUs immediately -> co-resident). WG (rt = blockIdx&15, sl = blockIdx>>4):
// rows rt*64..+64, h-cols sl*32..+32. Same-rt WGs share blockIdx%8 -> same XCD
// (perf heuristic only; correctness via device-scope fences/atomics).
// Wave (rfh = w>>1, ch = w&1): rows rfh*32..+32, cols ch*16..+16.
// Gate weights (48 frags) + W1 (16 frags) live in VGPRs for all 512 steps.
__global__ __launch_bounds__(256, 1) void gru_main(
    const float* __restrict__ X0, const float* __restrict__ V,
    const float* __restrict__ Wih, const float* __restrict__ bih,
    const float* __restrict__ bhh, const float* __restrict__ b1,
    const float* __restrict__ W2, const float* __restrict__ b2,
    const unsigned short* __restrict__ PW, const unsigned short* __restrict__ PW1,
    unsigned short* __restrict__ Hb, float* __restrict__ px,
    unsigned* __restrict__ bar, float* __restrict__ out)
{
  __shared__ alignas(16) float xg[BT][4];                 // [v0,v1,x0,x1] per row
  __shared__ alignas(16) unsigned short hstage[BT][SLC];  // h_t slice repack

  const int tid = threadIdx.x;
  const int l  = tid & 63, w = tid >> 6;
  const int lm = l & 15,  ld = l >> 4;
  const int rt = blockIdx.x & 15, sl = blockIdx.x >> 4;
  const int rfh = w >> 1, ch = w & 1;
  const int row0 = rt * BT;

  unsigned* cnt = bar + rt * 64;
  unsigned* gen = bar + rt * 64 + 32;

  // ---- persistent weight fragments in registers ----
  short8 BW[3][16];
  {
    const char* pwb = reinterpret_cast<const char*>(PW);
#pragma unroll
    for (int g = 0; g < 3; ++g)
#pragma unroll
      for (int kk = 0; kk < 16; ++kk)
        BW[g][kk] = *reinterpret_cast<const short8*>(
            pwb + (size_t)((((sl * 6 + g * 2 + ch) * 16 + kk) * 64 + l) * 16));
  }
  short8 BM[16];
  {
    const char* pw1b = reinterpret_cast<const char*>(PW1);
#pragma unroll
    for (int kk = 0; kk < 16; ++kk)
      BM[kk] = *reinterpret_cast<const short8*>(
          pw1b + (size_t)(((sl * 16 + kk) * 64 + l) * 16));
  }

  // ---- per-lane gate/MLP constants (column fixed across steps) ----
  const int jcol = sl * SLC + ch * 16 + lm;
  f32x4 wvx[3]; float bi[3], bh[3];
#pragma unroll
  for (int g = 0; g < 3; ++g) {
    int jg = g * 512 + jcol;
    wvx[g] = *reinterpret_cast<const f32x4*>(Wih + (size_t)jg * 4);
    bi[g] = bih[jg];
    bh[g] = bhh[jg];
  }
  const int ic = sl * 16 + lm;
  const float b1v = b1[ic];
  const float w2a = W2[ic], w2b = W2[256 + ic];
  const float b2c = b2[tid & 1];

  // ---- phase-C persistent x and input staging ----
  float xcur = 0.f;
  if (tid < BT * 2) {
    int row = tid >> 1, c = tid & 1;
    float x0 = X0[(row0 + row) * 2 + c];
    xcur = x0;
    xg[row][2 + c] = x0;
    xg[row][c] = V[(size_t)(row0 + row) * (Ssz * 2) + c];   // v_0
  }
  float hp[2][4];
#pragma unroll
  for (int i = 0; i < 2; ++i)
#pragma unroll
    for (int r = 0; r < 4; ++r) hp[i][r] = 0.f;
  __syncthreads();

  for (int t = 0; t < Ssz; ++t) {
    // ================= phase A: gates =================
    f32x4 acc[2][3];
#pragma unroll
    for (int i = 0; i < 2; ++i)
#pragma unroll
      for (int g = 0; g < 3; ++g) acc[i][g] = (f32x4){0.f, 0.f, 0.f, 0.f};

    if (t > 0) {
      const unsigned short* hprev = Hb + (size_t)((t & 1) ^ 1) * (1024 * 512);
      const unsigned short* base0 = hprev + (size_t)(row0 + rfh * 32 + lm) * 512 + ld * 8;
      const unsigned short* base1 = base0 + 16 * 512;
#pragma unroll
      for (int kk = 0; kk < 16; ++kk) {
        short8 a0 = *reinterpret_cast<const short8*>(base0 + kk * 32);
        short8 a1 = *reinterpret_cast<const short8*>(base1 + kk * 32);
        acc[0][0] = __builtin_amdgcn_mfma_f32_16x16x32_bf16(a0, BW[0][kk], acc[0][0], 0, 0, 0);
        acc[1][0] = __builtin_amdgcn_mfma_f32_16x16x32_bf16(a1, BW[0][kk], acc[1][0], 0, 0, 0);
        acc[0][1] = __builtin_amdgcn_mfma_f32_16x16x32_bf16(a0, BW[1][kk], acc[0][1], 0, 0, 0);
        acc[1][1] = __builtin_amdgcn_mfma_f32_16x16x32_bf16(a1, BW[1][kk], acc[1][1], 0, 0, 0);
        acc[0][2] = __builtin_amdgcn_mfma_f32_16x16x32_bf16(a0, BW[2][kk], acc[0][2], 0, 0, 0);
        acc[1][2] = __builtin_amdgcn_mfma_f32_16x16x32_bf16(a1, BW[2][kk], acc[1][2], 0, 0, 0);
      }
    }

    // gate math -> h_t (fp32 master in regs), stage bf16 slice in LDS
#pragma unroll
    for (int rf2 = 0; rf2 < 2; ++rf2) {
#pragma unroll
      for (int r = 0; r < 4; ++r) {
        const int m = rfh * 32 + rf2 * 16 + ld * 4 + r;
        const f32x4 xv = *reinterpret_cast<const f32x4*>(&xg[m][0]);
        float gv0 = wvx[0][0]*xv[0] + wvx[0][1]*xv[1] + wvx[0][2]*xv[2] + wvx[0][3]*xv[3];
        float gv1 = wvx[1][0]*xv[0] + wvx[1][1]*xv[1] + wvx[1][2]*xv[2] + wvx[1][3]*xv[3];
        float gv2 = wvx[2][0]*xv[0] + wvx[2][1]*xv[1] + wvx[2][2]*xv[2] + wvx[2][3]*xv[3];
        float rr = sigm(gv0 + bi[0] + bh[0] + acc[rf2][0][r]);
        float zz = sigm(gv1 + bi[1] + bh[1] + acc[rf2][1][r]);
        float nn = tanh_f(gv2 + bi[2] + rr * (acc[rf2][2][r] + bh[2]));
        float ht = (1.f - zz) * nn + zz * hp[rf2][r];
        hp[rf2][r] = ht;
        hstage[m][ch * 16 + lm] = f2bf(ht);
      }
    }
    __syncthreads();
    {   // coalesced copy: hstage -> Hbuf[t&1]
      unsigned short* hcur = Hb + (size_t)(t & 1) * (1024 * 512);
      int row = tid >> 2, q = tid & 3;
      *reinterpret_cast<short8*>(hcur + (size_t)(row0 + row) * 512 + sl * SLC + q * 8)
          = *reinterpret_cast<const short8*>(&hstage[row][q * 8]);
    }
    rtbar(cnt, gen);   // S1: h_t visible to rowtile

    // ================= phase B: residual MLP =================
    {
      const unsigned short* hcur = Hb + (size_t)(t & 1) * (1024 * 512);
      const unsigned short* baseB = hcur + (size_t)(row0 + w * 16 + lm) * 512 + ld * 8;
      f32x4 am = (f32x4){0.f, 0.f, 0.f, 0.f};
#pragma unroll
      for (int kk = 0; kk < 16; ++kk) {
        short8 a = *reinterpret_cast<const short8*>(baseB + kk * 32);
        am = __builtin_amdgcn_mfma_f32_16x16x32_bf16(a, BM[kk], am, 0, 0, 0);
      }
      float pa[4], pb[4];
#pragma unroll
      for (int r = 0; r < 4; ++r) {
        float mv = fmaxf(am[r] + b1v, 0.f);
        pa[r] = mv * w2a;
        pb[r] = mv * w2b;
      }
#pragma unroll
      for (int off = 1; off < 16; off <<= 1)
#pragma unroll
        for (int r = 0; r < 4; ++r) {
          pa[r] += __shfl_xor(pa[r], off);
          pb[r] += __shfl_xor(pb[r], off);
        }
      if (lm == 0) {
#pragma unroll
        for (int r = 0; r < 4; ++r) {
          f32x2 v2 = {pa[r], pb[r]};
          *reinterpret_cast<f32x2*>(px + (size_t)(((rt * 16 + sl) * 64) + w * 16 + ld * 4 + r) * 2) = v2;
        }
      }
    }
    rtbar(cnt, gen);   // S2: px visible to rowtile

    // ================= phase C: x update (WG-local) =================
    if (tid < BT * 2) {
      int row = tid >> 1, c = tid & 1;
      float s = b2c;
#pragma unroll
      for (int sx = 0; sx < 16; ++sx)
        s += px[(size_t)(((rt * 16 + sx) * 64) + row) * 2 + c];
      float vt = xg[row][c];
      float xt = xcur + vt + s;
      xcur = xt;
      if (sl == 0) out[(size_t)(row0 + row) * (Ssz * 2) + t * 2 + c] = xt;
      xg[row][2 + c] = xt;
      xg[row][c] = (t + 1 < Ssz) ? V[(size_t)(row0 + row) * (Ssz * 2) + (t + 1) * 2 + c] : 0.f;
    }
    __syncthreads();   // xg ready for next phase A
  }
}

extern "C" void kernel_launch(void* const* d_in, const int* in_sizes, int n_in,
                              void* d_out, int out_size, void* d_ws, size_t ws_size,
                              hipStream_t stream) {
  const float* X0  = (const float*)d_in[0];
  const float* V   = (const float*)d_in[1];
  const float* Wih = (const float*)d_in[2];
  const float* Whh = (const float*)d_in[3];
  const float* bih = (const float*)d_in[4];
  const float* bhh = (const float*)d_in[5];
  const float* W1  = (const float*)d_in[6];
  const float* b1  = (const float*)d_in[7];
  const float* W2  = (const float*)d_in[8];
  const float* b2  = (const float*)d_in[9];
  float* out = (float*)d_out;

  char* ws = (char*)d_ws;
  unsigned short* PW  = (unsigned short*)(ws + WS_PW);
  unsigned short* PW1 = (unsigned short*)(ws + WS_PW1);
  unsigned short* Hb  = (unsigned short*)(ws + WS_HB);
  float*          px  = (float*)(ws + WS_PX);
  unsigned*       bar = (unsigned*)(ws + WS_BAR);

  pack_whh_k<<<384, 256, 0, stream>>>(Whh, PW, bar);
  pack_w1_k<<<64, 256, 0, stream>>>(W1, PW1);
  gru_main<<<256, 256, 0, stream>>>(X0, V, Wih, bih, bhh, b1, W2, b2,
                                    PW, PW1, Hb, px, bar, out);
}

// Round 5
// 3966.758 us; speedup vs baseline: 8.5953x; 6.5803x over previous
//
#include <hip/hip_runtime.h>

#define Ssz 512
#define BT  64     // rows per rowtile
#define SLC 32     // h-cols per slice

typedef __attribute__((ext_vector_type(8))) short short8;
typedef __attribute__((ext_vector_type(4))) float f32x4;
typedef __attribute__((ext_vector_type(4))) unsigned uint4v;

// ---- ws layout (bytes) ----
#define WS_PW   0u            // 1.5 MB packed gate weights
#define WS_PW1  1572864u      // 256 KB packed W1
#define WS_HB   1835008u      // 2 MB Hbuf[2][1024][512] bf16
#define WS_PX   3932160u      // 128 KB px[16][64][2][16] f32
#define WS_BAR  4456448u      // flags[16][32] u32 (pack zeroes 4 KB)

__device__ __forceinline__ unsigned short f2bf(float f) {
  unsigned int u = __builtin_bit_cast(unsigned int, f);
  u += 0x7fffu + ((u >> 16) & 1u);   // RNE (finite inputs)
  return (unsigned short)(u >> 16);
}
__device__ __forceinline__ float sigm(float x) {
  x = fminf(fmaxf(x, -30.f), 30.f);
  return 1.f / (1.f + __expf(-x));
}
__device__ __forceinline__ float tanh_f(float x) {
  x = fminf(fmaxf(x, -15.f), 15.f);
  float e = __expf(2.f * x);
  return (e - 1.f) / (e + 1.f);
}

// ---- cache-bypassing (device-coherent) memory ops: data lives at MALL,
// never in L1/L2 -> no fences/invalidates needed anywhere. ----
__device__ __forceinline__ uint4v gload16(const void* p) {
  uint4v d;
  asm volatile("global_load_dwordx4 %0, %1, off sc0 sc1" : "=v"(d) : "v"(p));
  return d;
}
__device__ __forceinline__ void gstore16(void* p, uint4v v) {
  asm volatile("global_store_dwordx4 %0, %1, off sc0 sc1" :: "v"(p), "v"(v) : "memory");
}
__device__ __forceinline__ void gstore4(void* p, unsigned v) {
  asm volatile("global_store_dword %0, %1, off sc0 sc1" :: "v"(p), "v"(v) : "memory");
}
// Drain own VMEM (covers inline-asm ops the compiler doesn't track), and pin
// subsequent consumers below the wait (guide rule #18).
__device__ __forceinline__ void vwait0() {
  asm volatile("s_waitcnt vmcnt(0)" ::: "memory");
  __builtin_amdgcn_sched_barrier(0);
}

// Pack W_hh [1536,512] f32 -> fragment-ordered bf16.
// byte offset (((sl*6+q)*16+kk)*64+l)*16 ; q = gate*2+ch
// holds W_hh[gate*512 + sl*32 + ch*16 + (l&15)][kk*32 + (l>>4)*8 + e]
// Block 0 zeroes all barrier words every launch (replay determinism).
__global__ void pack_whh_k(const float* __restrict__ Wp, unsigned short* __restrict__ dst,
                           unsigned* __restrict__ barz) {
  if (blockIdx.x == 0) {
    for (int i = threadIdx.x; i < 1024; i += 256) barz[i] = 0u;
  }
  int T = blockIdx.x * 256 + threadIdx.x;
  int l  = T & 63;
  int r1 = T >> 6;
  int kk = r1 & 15;
  int r2 = r1 >> 4;
  int q  = r2 % 6;
  int sl = r2 / 6;
  int g = q >> 1, ch = q & 1;
  int j  = g * 512 + sl * 32 + ch * 16 + (l & 15);
  int kb = kk * 32 + (l >> 4) * 8;
  const float* src = Wp + j * 512 + kb;
  short8 o;
#pragma unroll
  for (int e = 0; e < 8; ++e) o[e] = (short)f2bf(src[e]);
  *reinterpret_cast<short8*>(dst + (size_t)T * 8) = o;
}

// Pack W1 [256,512] f32 -> fragment-ordered bf16.
__global__ void pack_w1_k(const float* __restrict__ W1, unsigned short* __restrict__ dst) {
  int T = blockIdx.x * 256 + threadIdx.x;
  int l  = T & 63;
  int r1 = T >> 6;
  int kk = r1 & 15;
  int sl = r1 >> 4;
  int j  = sl * 16 + (l & 15);
  int kb = kk * 32 + (l >> 4) * 8;
  const float* src = W1 + j * 512 + kb;
  short8 o;
#pragma unroll
  for (int e = 0; e < 8; ++e) o[e] = (short)f2bf(src[e]);
  *reinterpret_cast<short8*>(dst + (size_t)T * 8) = o;
}

// swizzled hfull byte address: row-major [64][512] bf16 with XOR on bits 4..6
__device__ __forceinline__ int haddr(int rowbase, int sw, int ld, int kk) {
  return rowbase + (((ld << 4) + (kk << 6)) ^ sw);
}

// 256 WGs x 256 threads, plain launch (grid == CU count -> co-resident).
// WG (rt=blockIdx&15, sl=blockIdx>>4): rows rt*64..+64, h-cols sl*32..+32.
// Flag barriers: monotonic epoch flags, bypass stores/loads, no fences, no RMW.
// Per iter i (0..512): [waitS1 -> FILL hfull(LDS) -> MLP(i-1)+arriveS2 ->
// ghMFMA(i) -> waitS2 -> xupdate(i-1)+out] then [gatemath h_i -> publish ->
// arriveS1(i+1)].
__global__ __launch_bounds__(256, 1) void gru_main(
    const float* __restrict__ X0, const float* __restrict__ V,
    const float* __restrict__ Wih, const float* __restrict__ bih,
    const float* __restrict__ bhh, const float* __restrict__ b1,
    const float* __restrict__ W2, const float* __restrict__ b2,
    const unsigned short* __restrict__ PW, const unsigned short* __restrict__ PW1,
    unsigned short* __restrict__ Hb, float* __restrict__ px,
    unsigned* __restrict__ bar, float* __restrict__ out)
{
  __shared__ alignas(16) unsigned short hfull[BT * 512];   // 64 KB, swizzled
  __shared__ alignas(16) unsigned short hstage[BT][40];    // 5 KB (40: bank spread)
  __shared__ alignas(16) float xg[BT][4];                  // [v0,v1,x0,x1]

  const int tid = threadIdx.x;
  const int l  = tid & 63, w = tid >> 6;
  const int lm = l & 15,  ld = l >> 4;
  const int rt = blockIdx.x & 15, sl = blockIdx.x >> 4;
  const int rfh = w >> 1, ch = w & 1;
  const int row0 = rt * BT;
  char* hfullB = reinterpret_cast<char*>(hfull);

  unsigned* fl1 = bar + rt * 32;        // S1 flags: h published
  unsigned* fl2 = fl1 + 16;             // S2 flags: px published

  // ---- persistent weight fragments in registers (loaded once) ----
  short8 BW[3][16];
  {
    const char* pwb = reinterpret_cast<const char*>(PW);
#pragma unroll
    for (int g = 0; g < 3; ++g)
#pragma unroll
      for (int kk = 0; kk < 16; ++kk)
        BW[g][kk] = *reinterpret_cast<const short8*>(
            pwb + (size_t)((((sl * 6 + g * 2 + ch) * 16 + kk) * 64 + l) * 16));
  }
  short8 BM[16];
  {
    const char* pw1b = reinterpret_cast<const char*>(PW1);
#pragma unroll
    for (int kk = 0; kk < 16; ++kk)
      BM[kk] = *reinterpret_cast<const short8*>(
          pw1b + (size_t)(((sl * 16 + kk) * 64 + l) * 16));
  }

  // ---- per-lane constants ----
  const int jcol = sl * SLC + ch * 16 + lm;
  f32x4 wvx[3]; float bi[3], bh[3];
#pragma unroll
  for (int g = 0; g < 3; ++g) {
    int jg = g * 512 + jcol;
    wvx[g] = *reinterpret_cast<const f32x4*>(Wih + (size_t)jg * 4);
    bi[g] = bih[jg];
    bh[g] = bhh[jg];
  }
  const int ic = sl * 16 + lm;
  const float b1v = b1[ic];
  const float w2a = W2[ic], w2b = W2[256 + ic];
  const float b2c = b2[tid & 1];

  float xcur = 0.f;
  if (tid < BT * 2) {
    int row = tid >> 1, c = tid & 1;
    float x0 = X0[(row0 + row) * 2 + c];
    xcur = x0;
    xg[row][2 + c] = x0;
    xg[row][c] = V[(size_t)(row0 + row) * (Ssz * 2) + c];   // v_0
  }
  float hp[2][4];
#pragma unroll
  for (int q = 0; q < 2; ++q)
#pragma unroll
    for (int r = 0; r < 4; ++r) hp[q][r] = 0.f;
  __syncthreads();

  const int rbA0 = (rfh * 32 + lm) * 1024,      swA0 = ((rfh * 32 + lm) & 7) << 4;
  const int rbA1 = (rfh * 32 + 16 + lm) * 1024, swA1 = ((rfh * 32 + 16 + lm) & 7) << 4;
  const int rbB  = (w * 16 + lm) * 1024,        swB  = ((w * 16 + lm) & 7) << 4;

  for (int i = 0; i <= Ssz; ++i) {
    f32x4 acc[2][3];
#pragma unroll
    for (int q = 0; q < 2; ++q)
#pragma unroll
      for (int g = 0; g < 3; ++g) acc[q][g] = (f32x4){0.f, 0.f, 0.f, 0.f};

    if (i > 0) {
      // ---- wait S1(i): peers' h_{i-1} at MALL ----
      if (tid == 0) {
        for (;;) {
          uint4v x0 = gload16(fl1 + 0),  x1 = gload16(fl1 + 4);
          uint4v x2 = gload16(fl1 + 8),  x3 = gload16(fl1 + 12);
          vwait0();
          unsigned mn = x0[0];
#pragma unroll
          for (int s = 1; s < 4; ++s) mn = min(mn, x0[s]);
#pragma unroll
          for (int s = 0; s < 4; ++s) { mn = min(mn, x1[s]); mn = min(mn, x2[s]); mn = min(mn, x3[s]); }
          if (mn >= (unsigned)i) break;
          __builtin_amdgcn_s_sleep(2);
        }
      }
      __syncthreads();

      // ---- FILL: h_{i-1} full rowtile -> swizzled LDS (64 KB) ----
      {
        const unsigned short* hsrc = Hb + (size_t)((i - 1) & 1) * (1024 * 512)
                                        + (size_t)row0 * 512;
        uint4v fb[16];
#pragma unroll
        for (int j = 0; j < 16; ++j)
          fb[j] = gload16(hsrc + (size_t)(tid + 256 * j) * 8);
        vwait0();
#pragma unroll
        for (int j = 0; j < 16; ++j) {
          int c = tid + 256 * j;
          int row = c >> 6, c16 = c & 63;
          *reinterpret_cast<uint4v*>(hfullB + row * 1024 + ((c16 * 16) ^ ((row & 7) << 4))) = fb[j];
        }
      }
      __syncthreads();

      // ---- MLP on h_{i-1}: px partial -> publish -> arrive S2(i) ----
      {
        f32x4 am = (f32x4){0.f, 0.f, 0.f, 0.f};
#pragma unroll
        for (int kk = 0; kk < 16; ++kk) {
          short8 a = *reinterpret_cast<const short8*>(hfullB + haddr(rbB, swB, ld, kk));
          am = __builtin_amdgcn_mfma_f32_16x16x32_bf16(a, BM[kk], am, 0, 0, 0);
        }
        float pa[4], pb[4];
#pragma unroll
        for (int r = 0; r < 4; ++r) {
          float mv = fmaxf(am[r] + b1v, 0.f);
          pa[r] = mv * w2a;
          pb[r] = mv * w2b;
        }
#pragma unroll
        for (int off = 1; off < 16; off <<= 1)
#pragma unroll
          for (int r = 0; r < 4; ++r) {
            pa[r] += __shfl_xor(pa[r], off);
            pb[r] += __shfl_xor(pb[r], off);
          }
        if (lm == 0) {
#pragma unroll
          for (int r = 0; r < 4; ++r) {
            int row = w * 16 + ld * 4 + r;
            float* p0 = px + ((size_t)(rt * 64 + row) * 2 + 0) * 16 + sl;
            float* p1 = px + ((size_t)(rt * 64 + row) * 2 + 1) * 16 + sl;
            gstore4(p0, __builtin_bit_cast(unsigned, pa[r]));
            gstore4(p1, __builtin_bit_cast(unsigned, pb[r]));
          }
        }
      }
      asm volatile("s_waitcnt vmcnt(0)" ::: "memory");  // own px stores at MALL
      __syncthreads();                                  // all waves drained
      if (tid == 0) gstore4(fl2 + sl, (unsigned)i);     // arrive S2(i)

      // ---- gh GEMM for step i (overlaps peers' MLP + S2 skew) ----
#pragma unroll
      for (int kk = 0; kk < 16; ++kk) {
        short8 a0 = *reinterpret_cast<const short8*>(hfullB + haddr(rbA0, swA0, ld, kk));
        short8 a1 = *reinterpret_cast<const short8*>(hfullB + haddr(rbA1, swA1, ld, kk));
        acc[0][0] = __builtin_amdgcn_mfma_f32_16x16x32_bf16(a0, BW[0][kk], acc[0][0], 0, 0, 0);
        acc[1][0] = __builtin_amdgcn_mfma_f32_16x16x32_bf16(a1, BW[0][kk], acc[1][0], 0, 0, 0);
        acc[0][1] = __builtin_amdgcn_mfma_f32_16x16x32_bf16(a0, BW[1][kk], acc[0][1], 0, 0, 0);
        acc[1][1] = __builtin_amdgcn_mfma_f32_16x16x32_bf16(a1, BW[1][kk], acc[1][1], 0, 0, 0);
        acc[0][2] = __builtin_amdgcn_mfma_f32_16x16x32_bf16(a0, BW[2][kk], acc[0][2], 0, 0, 0);
        acc[1][2] = __builtin_amdgcn_mfma_f32_16x16x32_bf16(a1, BW[2][kk], acc[1][2], 0, 0, 0);
      }

      // ---- wait S2(i): peers' px at MALL ----
      if (tid == 0) {
        for (;;) {
          uint4v x0 = gload16(fl2 + 0),  x1 = gload16(fl2 + 4);
          uint4v x2 = gload16(fl2 + 8),  x3 = gload16(fl2 + 12);
          vwait0();
          unsigned mn = x0[0];
#pragma unroll
          for (int s = 1; s < 4; ++s) mn = min(mn, x0[s]);
#pragma unroll
          for (int s = 0; s < 4; ++s) { mn = min(mn, x1[s]); mn = min(mn, x2[s]); mn = min(mn, x3[s]); }
          if (mn >= (unsigned)i) break;
          __builtin_amdgcn_s_sleep(2);
        }
      }
      __syncthreads();

      // ---- x update: x_{i-1} = x_{i-2} + v_{i-1} + res; write out; stage xg ----
      if (tid < BT * 2) {
        int row = tid >> 1, c = tid & 1;
        const float* pc = px + ((size_t)(rt * 64 + row) * 2 + c) * 16;
        f32x4 s0 = __builtin_bit_cast(f32x4, gload16(pc + 0));
        f32x4 s1 = __builtin_bit_cast(f32x4, gload16(pc + 4));
        f32x4 s2 = __builtin_bit_cast(f32x4, gload16(pc + 8));
        f32x4 s3 = __builtin_bit_cast(f32x4, gload16(pc + 12));
        vwait0();
        float s = b2c;
#pragma unroll
        for (int r = 0; r < 4; ++r) s += s0[r] + s1[r] + s2[r] + s3[r];
        float vprev = xg[row][c];
        float xt = xcur + vprev + s;
        xcur = xt;
        if (sl == 0) out[(size_t)(row0 + row) * (Ssz * 2) + (i - 1) * 2 + c] = xt;
        xg[row][2 + c] = xt;
        xg[row][c] = (i < Ssz) ? V[(size_t)(row0 + row) * (Ssz * 2) + i * 2 + c] : 0.f;
      }
      __syncthreads();   // xg ready
    }

    if (i < Ssz) {
      // ---- gate math -> h_i (regs) + hstage ----
#pragma unroll
      for (int rf2 = 0; rf2 < 2; ++rf2) {
#pragma unroll
        for (int r = 0; r < 4; ++r) {
          const int m = rfh * 32 + rf2 * 16 + ld * 4 + r;
          const f32x4 xv = *reinterpret_cast<const f32x4*>(&xg[m][0]);
          float gv0 = wvx[0][0]*xv[0] + wvx[0][1]*xv[1] + wvx[0][2]*xv[2] + wvx[0][3]*xv[3];
          float gv1 = wvx[1][0]*xv[0] + wvx[1][1]*xv[1] + wvx[1][2]*xv[2] + wvx[1][3]*xv[3];
          float gv2 = wvx[2][0]*xv[0] + wvx[2][1]*xv[1] + wvx[2][2]*xv[2] + wvx[2][3]*xv[3];
          float rr = sigm(gv0 + bi[0] + bh[0] + acc[rf2][0][r]);
          float zz = sigm(gv1 + bi[1] + bh[1] + acc[rf2][1][r]);
          float nn = tanh_f(gv2 + bi[2] + rr * (acc[rf2][2][r] + bh[2]));
          float ht = (1.f - zz) * nn + zz * hp[rf2][r];
          hp[rf2][r] = ht;
          hstage[m][ch * 16 + lm] = f2bf(ht);
        }
      }
      __syncthreads();

      // ---- publish h_i slice (bypass) + arrive S1(i+1) ----
      {
        int row = tid >> 2, seg = tid & 3;
        uint4v hv = *reinterpret_cast<const uint4v*>(&hstage[row][seg * 8]);
        gstore16(Hb + (size_t)(i & 1) * (1024 * 512)
                    + (size_t)(row0 + row) * 512 + sl * SLC + seg * 8, hv);
      }
      asm volatile("s_waitcnt vmcnt(0)" ::: "memory");
      __syncthreads();
      if (tid == 0) gstore4(fl1 + sl, (unsigned)(i + 1));
    }
  }
}

extern "C" void kernel_launch(void* const* d_in, const int* in_sizes, int n_in,
                              void* d_out, int out_size, void* d_ws, size_t ws_size,
                              hipStream_t stream) {
  const float* X0  = (const float*)d_in[0];
  const float* V   = (const float*)d_in[1];
  const float* Wih = (const float*)d_in[2];
  const float* Whh = (const float*)d_in[3];
  const float* bih = (const float*)d_in[4];
  const float* bhh = (const float*)d_in[5];
  const float* W1  = (const float*)d_in[6];
  const float* b1  = (const float*)d_in[7];
  const float* W2  = (const float*)d_in[8];
  const float* b2  = (const float*)d_in[9];
  float* out = (float*)d_out;

  char* ws = (char*)d_ws;
  unsigned short* PW  = (unsigned short*)(ws + WS_PW);
  unsigned short* PW1 = (unsigned short*)(ws + WS_PW1);
  unsigned short* Hb  = (unsigned short*)(ws + WS_HB);
  float*          px  = (float*)(ws + WS_PX);
  unsigned*       bar = (unsigned*)(ws + WS_BAR);

  pack_whh_k<<<384, 256, 0, stream>>>(Whh, PW, bar);
  pack_w1_k<<<64, 256, 0, stream>>>(W1, PW1);
  gru_main<<<256, 256, 0, stream>>>(X0, V, Wih, bih, bhh, b1, W2, b2,
                                    PW, PW1, Hb, px, bar, out);
}

// Round 9
// 3930.922 us; speedup vs baseline: 8.6736x; 1.0091x over previous
//
#include <hip/hip_runtime.h>

#define Ssz 512
#define BT  64     // rows per rowtile
#define SLC 32     // h-cols per slice

typedef __attribute__((ext_vector_type(8))) short short8;
typedef __attribute__((ext_vector_type(4))) float f32x4;
typedef __attribute__((ext_vector_type(2))) float f32x2;
typedef __attribute__((ext_vector_type(4))) unsigned uint4v;
typedef __attribute__((ext_vector_type(2))) unsigned uint2v;

// ---- ws layout (bytes) ----
#define WS_PW   0u            // 1.5 MB packed gate weights
#define WS_PW1  1572864u      // 256 KB packed W1
#define WS_HB   1835008u      // 2 MB Hbuf[2][1024][512] bf16
#define WS_PX   3932160u      // 128 KB px[rt16][row64][c2][sl16] f32
#define WS_BAR  4456448u      // flags[16][32] u32 (pack zeroes 4 KB)

__device__ __forceinline__ unsigned short f2bf(float f) {
  unsigned int u = __builtin_bit_cast(unsigned int, f);
  u += 0x7fffu + ((u >> 16) & 1u);   // RNE (finite inputs)
  return (unsigned short)(u >> 16);
}
__device__ __forceinline__ float sigm(float x) {
  x = fminf(fmaxf(x, -30.f), 30.f);
  return 1.f / (1.f + __expf(-x));
}
__device__ __forceinline__ float tanh_f(float x) {
  x = fminf(fmaxf(x, -15.f), 15.f);
  float e = __expf(2.f * x);
  return (e - 1.f) / (e + 1.f);
}

// ---- cache-bypassing (device-coherent) memory ops: data lives at MALL,
// never in L1/L2 -> no fences/invalidates needed anywhere. ----
__device__ __forceinline__ uint4v gload16(const void* p) {
  uint4v d;
  asm volatile("global_load_dwordx4 %0, %1, off sc0 sc1" : "=v"(d) : "v"(p));
  return d;
}
__device__ __forceinline__ unsigned gload4(const void* p) {
  unsigned d;
  asm volatile("global_load_dword %0, %1, off sc0 sc1" : "=v"(d) : "v"(p));
  return d;
}
__device__ __forceinline__ void gstore16(void* p, uint4v v) {
  asm volatile("global_store_dwordx4 %0, %1, off sc0 sc1" :: "v"(p), "v"(v) : "memory");
}
__device__ __forceinline__ void gstore4(void* p, unsigned v) {
  asm volatile("global_store_dword %0, %1, off sc0 sc1" :: "v"(p), "v"(v) : "memory");
}
__device__ __forceinline__ void vwait0() {
  asm volatile("s_waitcnt vmcnt(0)" ::: "memory");
  __builtin_amdgcn_sched_barrier(0);
}

// Pack W_hh [1536,512] f32 -> fragment-ordered bf16 (R5 layout, unchanged).
// byte offset (((sl*6+q)*16+kk)*64+l)*16 ; q = gate*2+ch
// holds W_hh[gate*512 + sl*32 + ch*16 + (l&15)][kk*32 + (l>>4)*8 + e]
// Block 0 zeroes all barrier words every launch (replay determinism).
__global__ void pack_whh_k(const float* __restrict__ Wp, unsigned short* __restrict__ dst,
                           unsigned* __restrict__ barz) {
  if (blockIdx.x == 0) {
    for (int i = threadIdx.x; i < 1024; i += 256) barz[i] = 0u;
  }
  int T = blockIdx.x * 256 + threadIdx.x;
  int l  = T & 63;
  int r1 = T >> 6;
  int kk = r1 & 15;
  int r2 = r1 >> 4;
  int q  = r2 % 6;
  int sl = r2 / 6;
  int g = q >> 1, ch = q & 1;
  int j  = g * 512 + sl * 32 + ch * 16 + (l & 15);
  int kb = kk * 32 + (l >> 4) * 8;
  const float* src = Wp + j * 512 + kb;
  short8 o;
#pragma unroll
  for (int e = 0; e < 8; ++e) o[e] = (short)f2bf(src[e]);
  *reinterpret_cast<short8*>(dst + (size_t)T * 8) = o;
}

// Pack W1 [256,512] f32 -> fragment-ordered bf16 (unchanged).
__global__ void pack_w1_k(const float* __restrict__ W1, unsigned short* __restrict__ dst) {
  int T = blockIdx.x * 256 + threadIdx.x;
  int l  = T & 63;
  int r1 = T >> 6;
  int kk = r1 & 15;
  int sl = r1 >> 4;
  int j  = sl * 16 + (l & 15);
  int kb = kk * 32 + (l >> 4) * 8;
  const float* src = W1 + j * 512 + kb;
  short8 o;
#pragma unroll
  for (int e = 0; e < 8; ++e) o[e] = (short)f2bf(src[e]);
  *reinterpret_cast<short8*>(dst + (size_t)T * 8) = o;
}

// swizzled hfull byte address: row-major [64][512] bf16 with XOR on bits 4..6
__device__ __forceinline__ int haddr(int rowbase, int sw, int ld, int kk) {
  return rowbase + (((ld << 4) + (kk << 6)) ^ sw);
}

// 256 WGs x 256 threads, plain launch (grid == CU count -> co-resident).
// IDENTICAL structure to the verified R5 kernel except three sync-shape
// deltas: (1) all-lane flag polls (lane polls one flag, __all) instead of
// tid0 min-scans; (2) wave-local FILL (wave w fills rows w*16..+16) so MLP
// reads only own-wave rows -> post-S1 and post-FILL __syncthreads deleted
// (the post-px barrier already orders all FILLs before the gh GEMM);
// (3) waves 2,3 skip the S2 poll (they only need the xg barrier).
__global__ __launch_bounds__(256, 1) void gru_main(
    const float* __restrict__ X0, const float* __restrict__ V,
    const float* __restrict__ Wih, const float* __restrict__ bih,
    const float* __restrict__ bhh, const float* __restrict__ b1,
    const float* __restrict__ W2, const float* __restrict__ b2,
    const unsigned short* __restrict__ PW, const unsigned short* __restrict__ PW1,
    unsigned short* __restrict__ Hb, float* __restrict__ px,
    unsigned* __restrict__ bar, float* __restrict__ out)
{
  __shared__ alignas(16) unsigned short hfull[BT * 512];   // 64 KB, swizzled
  __shared__ alignas(16) unsigned short hstage[BT][40];    // 5 KB
  __shared__ alignas(16) float xg[BT][4];                  // [v0,v1,x0,x1]

  const int tid = threadIdx.x;
  const int l  = tid & 63, w = tid >> 6;
  const int lm = l & 15,  ld = l >> 4;
  const int rt = blockIdx.x & 15, sl = blockIdx.x >> 4;
  const int rfh = w >> 1, ch = w & 1;
  const int row0 = rt * BT;
  char* hfullB = reinterpret_cast<char*>(hfull);

  unsigned* fl1 = bar + rt * 32;        // S1 flags: h published (value = step+1)
  unsigned* fl2 = fl1 + 16;             // S2 flags: px published (value = step)

  // ---- persistent weight fragments in registers (loaded once) ----
  short8 BW[3][16];
  {
    const char* pwb = reinterpret_cast<const char*>(PW);
#pragma unroll
    for (int g = 0; g < 3; ++g)
#pragma unroll
      for (int kk = 0; kk < 16; ++kk)
        BW[g][kk] = *reinterpret_cast<const short8*>(
            pwb + (size_t)((((sl * 6 + g * 2 + ch) * 16 + kk) * 64 + l) * 16));
  }
  short8 BM[16];
  {
    const char* pw1b = reinterpret_cast<const char*>(PW1);
#pragma unroll
    for (int kk = 0; kk < 16; ++kk)
      BM[kk] = *reinterpret_cast<const short8*>(
          pw1b + (size_t)(((sl * 16 + kk) * 64 + l) * 16));
  }

  // ---- per-lane constants ----
  const int jcol = sl * SLC + ch * 16 + lm;
  f32x4 wvx[3]; float bi[3], bh[3];
#pragma unroll
  for (int g = 0; g < 3; ++g) {
    int jg = g * 512 + jcol;
    wvx[g] = *reinterpret_cast<const f32x4*>(Wih + (size_t)jg * 4);
    bi[g] = bih[jg];
    bh[g] = bhh[jg];
  }
  const int ic = sl * 16 + lm;
  const float b1v = b1[ic];
  const float w2a = W2[ic], w2b = W2[256 + ic];
  const float b2c = b2[tid & 1];

  float xcur = 0.f;
  if (tid < BT * 2) {
    int row = tid >> 1, c = tid & 1;
    float x0 = X0[(row0 + row) * 2 + c];
    xcur = x0;
    xg[row][2 + c] = x0;
    xg[row][c] = V[(size_t)(row0 + row) * (Ssz * 2) + c];   // v_0
  }
  float hp[2][4];
#pragma unroll
  for (int q = 0; q < 2; ++q)
#pragma unroll
    for (int r = 0; r < 4; ++r) hp[q][r] = 0.f;
  __syncthreads();

  const int rbA0 = (rfh * 32 + lm) * 1024,      swA0 = ((rfh * 32 + lm) & 7) << 4;
  const int rbA1 = (rfh * 32 + 16 + lm) * 1024, swA1 = ((rfh * 32 + 16 + lm) & 7) << 4;
  const int rbB  = (w * 16 + lm) * 1024,        swB  = ((w * 16 + lm) & 7) << 4;

  for (int i = 0; i <= Ssz; ++i) {
    f32x4 acc[2][3];
#pragma unroll
    for (int q = 0; q < 2; ++q)
#pragma unroll
      for (int g = 0; g < 3; ++g) acc[q][g] = (f32x4){0.f, 0.f, 0.f, 0.f};

    if (i > 0) {
      // ---- poll S1(i): all 16 producer WGs published h_{i-1} (all-lane) ----
      {
        const unsigned* fp = fl1 + (l & 15);
        for (;;) {
          unsigned v = gload4(fp);
          vwait0();
          if (__all((int)(v >= (unsigned)i))) break;
          __builtin_amdgcn_s_sleep(1);
        }
      }
      // (no barrier: FILL below is wave-local)

      // ---- FILL: wave w stages rows w*16..+16 of h_{i-1} -> swizzled LDS ----
      {
        const char* hsrc = reinterpret_cast<const char*>(
            Hb + (size_t)((i - 1) & 1) * (1024 * 512) + (size_t)row0 * 512);
        uint4v fb[16];
#pragma unroll
        for (int j = 0; j < 16; ++j)
          fb[j] = gload16(hsrc + (size_t)(w * 16 + j) * 1024 + l * 16);
        vwait0();
#pragma unroll
        for (int j = 0; j < 16; ++j) {
          const int m = w * 16 + j;
          *reinterpret_cast<uint4v*>(hfullB + m * 1024 + ((l * 16) ^ ((m & 7) << 4))) = fb[j];
        }
      }
      // (no barrier: MLP reads only this wave's rows)

      // ---- MLP on rows w*16..+16 of h_{i-1}: px partial -> publish ----
      {
        f32x4 am = (f32x4){0.f, 0.f, 0.f, 0.f};
#pragma unroll
        for (int kk = 0; kk < 16; ++kk) {
          short8 a = *reinterpret_cast<const short8*>(hfullB + haddr(rbB, swB, ld, kk));
          am = __builtin_amdgcn_mfma_f32_16x16x32_bf16(a, BM[kk], am, 0, 0, 0);
        }
        float pa[4], pb[4];
#pragma unroll
        for (int r = 0; r < 4; ++r) {
          float mv = fmaxf(am[r] + b1v, 0.f);
          pa[r] = mv * w2a;
          pb[r] = mv * w2b;
        }
#pragma unroll
        for (int off = 1; off < 16; off <<= 1)
#pragma unroll
          for (int r = 0; r < 4; ++r) {
            pa[r] += __shfl_xor(pa[r], off);
            pb[r] += __shfl_xor(pb[r], off);
          }
        if (lm == 0) {
#pragma unroll
          for (int r = 0; r < 4; ++r) {
            int row = w * 16 + ld * 4 + r;
            float* p0 = px + ((size_t)(rt * 64 + row) * 2 + 0) * 16 + sl;
            float* p1 = px + ((size_t)(rt * 64 + row) * 2 + 1) * 16 + sl;
            gstore4(p0, __builtin_bit_cast(unsigned, pa[r]));
            gstore4(p1, __builtin_bit_cast(unsigned, pb[r]));
          }
        }
      }
      asm volatile("s_waitcnt vmcnt(0)" ::: "memory");  // own px stores at MALL
      __syncthreads();          // all waves: px drained AND all FILLs in LDS
      if (tid == 0) gstore4(fl2 + sl, (unsigned)i);     // arrive S2(i)

      // ---- gh GEMM for step i (overlaps peers' MLP + S2 skew) ----
      if (i < Ssz) {
#pragma unroll
        for (int kk = 0; kk < 16; ++kk) {
          short8 a0 = *reinterpret_cast<const short8*>(hfullB + haddr(rbA0, swA0, ld, kk));
          short8 a1 = *reinterpret_cast<const short8*>(hfullB + haddr(rbA1, swA1, ld, kk));
          acc[0][0] = __builtin_amdgcn_mfma_f32_16x16x32_bf16(a0, BW[0][kk], acc[0][0], 0, 0, 0);
          acc[1][0] = __builtin_amdgcn_mfma_f32_16x16x32_bf16(a1, BW[0][kk], acc[1][0], 0, 0, 0);
          acc[0][1] = __builtin_amdgcn_mfma_f32_16x16x32_bf16(a0, BW[1][kk], acc[0][1], 0, 0, 0);
          acc[1][1] = __builtin_amdgcn_mfma_f32_16x16x32_bf16(a1, BW[1][kk], acc[1][1], 0, 0, 0);
          acc[0][2] = __builtin_amdgcn_mfma_f32_16x16x32_bf16(a0, BW[2][kk], acc[0][2], 0, 0, 0);
          acc[1][2] = __builtin_amdgcn_mfma_f32_16x16x32_bf16(a1, BW[2][kk], acc[1][2], 0, 0, 0);
        }
      }

      // ---- poll S2(i): peers' px at MALL (waves 0,1 only; all-lane) ----
      if (w < 2) {
        const unsigned* fp = fl2 + (l & 15);
        for (;;) {
          unsigned v = gload4(fp);
          vwait0();
          if (__all((int)(v >= (unsigned)i))) break;
          __builtin_amdgcn_s_sleep(1);
        }
      }
      // ---- x update: x_{i-1} = x_{i-2} + v_{i-1} + res; write out; stage xg ----
      if (tid < BT * 2) {
        int row = tid >> 1, c = tid & 1;
        const float* pc = px + ((size_t)(rt * 64 + row) * 2 + c) * 16;
        f32x4 s0 = __builtin_bit_cast(f32x4, gload16(pc + 0));
        f32x4 s1 = __builtin_bit_cast(f32x4, gload16(pc + 4));
        f32x4 s2 = __builtin_bit_cast(f32x4, gload16(pc + 8));
        f32x4 s3 = __builtin_bit_cast(f32x4, gload16(pc + 12));
        vwait0();
        float s = b2c;
#pragma unroll
        for (int r = 0; r < 4; ++r) s += s0[r] + s1[r] + s2[r] + s3[r];
        float vprev = xg[row][c];
        float xt = xcur + vprev + s;
        xcur = xt;
        if (sl == 0) out[(size_t)(row0 + row) * (Ssz * 2) + (i - 1) * 2 + c] = xt;
        xg[row][2 + c] = xt;
        xg[row][c] = (i < Ssz) ? V[(size_t)(row0 + row) * (Ssz * 2) + i * 2 + c] : 0.f;
      }
      __syncthreads();   // xg ready for all waves' gate math
    }

    if (i < Ssz) {
      // ---- gate math -> h_i (regs) + hstage ----
#pragma unroll
      for (int rf2 = 0; rf2 < 2; ++rf2) {
#pragma unroll
        for (int r = 0; r < 4; ++r) {
          const int m = rfh * 32 + rf2 * 16 + ld * 4 + r;
          const f32x4 xv = *reinterpret_cast<const f32x4*>(&xg[m][0]);
          float gv0 = wvx[0][0]*xv[0] + wvx[0][1]*xv[1] + wvx[0][2]*xv[2] + wvx[0][3]*xv[3];
          float gv1 = wvx[1][0]*xv[0] + wvx[1][1]*xv[1] + wvx[1][2]*xv[2] + wvx[1][3]*xv[3];
          float gv2 = wvx[2][0]*xv[0] + wvx[2][1]*xv[1] + wvx[2][2]*xv[2] + wvx[2][3]*xv[3];
          float rr = sigm(gv0 + bi[0] + bh[0] + acc[rf2][0][r]);
          float zz = sigm(gv1 + bi[1] + bh[1] + acc[rf2][1][r]);
          float nn = tanh_f(gv2 + bi[2] + rr * (acc[rf2][2][r] + bh[2]));
          float ht = (1.f - zz) * nn + zz * hp[rf2][r];
          hp[rf2][r] = ht;
          hstage[m][ch * 16 + lm] = f2bf(ht);
        }
      }
      __syncthreads();

      // ---- publish h_i slice (bypass) + arrive S1(i+1) ----
      {
        int row = tid >> 2, seg = tid & 3;
        uint4v hv = *reinterpret_cast<const uint4v*>(&hstage[row][seg * 8]);
        gstore16(Hb + (size_t)(i & 1) * (1024 * 512)
                    + (size_t)(row0 + row) * 512 + sl * SLC + seg * 8, hv);
      }
      asm volatile("s_waitcnt vmcnt(0)" ::: "memory");
      __syncthreads();
      if (tid == 0) gstore4(fl1 + sl, (unsigned)(i + 1));
    }
  }
}

extern "C" void kernel_launch(void* const* d_in, const int* in_sizes, int n_in,
                              void* d_out, int out_size, void* d_ws, size_t ws_size,
                              hipStream_t stream) {
  const float* X0  = (const float*)d_in[0];
  const float* V   = (const float*)d_in[1];
  const float* Wih = (const float*)d_in[2];
  const float* Whh = (const float*)d_in[3];
  const float* bih = (const float*)d_in[4];
  const float* bhh = (const float*)d_in[5];
  const float* W1  = (const float*)d_in[6];
  const float* b1  = (const float*)d_in[7];
  const float* W2  = (const float*)d_in[8];
  const float* b2  = (const float*)d_in[9];
  float* out = (float*)d_out;

  char* ws = (char*)d_ws;
  unsigned short* PW  = (unsigned short*)(ws + WS_PW);
  unsigned short* PW1 = (unsigned short*)(ws + WS_PW1);
  unsigned short* Hb  = (unsigned short*)(ws + WS_HB);
  float*          px  = (float*)(ws + WS_PX);
  unsigned*       bar = (unsigned*)(ws + WS_BAR);

  pack_whh_k<<<384, 256, 0, stream>>>(Whh, PW, bar);
  pack_w1_k<<<64, 256, 0, stream>>>(W1, PW1);
  gru_main<<<256, 256, 0, stream>>>(X0, V, Wih, bih, bhh, b1, W2, b2,
                                    PW, PW1, Hb, px, bar, out);
}